// Round 6
// baseline (112.765 us; speedup 1.0000x reference)
//
#include <hip/hip_runtime.h>
#include <math.h>

#define NEI 15
#define ROWSTRIDE 16     // pad neighbor rows to 16 ints for int4 loads

#define FLAG_INVALID 0
#define FLAG_AGG     1
#define FLAG_PREFIX  2

typedef float f4 __attribute__((ext_vector_type(4)));

// Compile-time component select from 4 int4s (K must be a constant after unroll)
#define GET16(n0, n1, n2, n3, K)                                   \
    ((K) < 8                                                       \
         ? ((K) < 4                                                \
                ? ((K) == 0 ? (n0).x : (K) == 1 ? (n0).y           \
                                : (K) == 2 ? (n0).z : (n0).w)      \
                : ((K) == 4 ? (n1).x : (K) == 5 ? (n1).y           \
                                : (K) == 6 ? (n1).z : (n1).w))     \
         : ((K) < 12                                               \
                ? ((K) == 8 ? (n2).x : (K) == 9 ? (n2).y           \
                                : (K) == 10 ? (n2).z : (n2).w)     \
                : ((K) == 12 ? (n3).x : (K) == 13 ? (n3).y         \
                                : (K) == 14 ? (n3).z : (n3).w)))

__device__ __forceinline__ int mbcnt64(unsigned long long m) {
    int c = __builtin_amdgcn_mbcnt_lo((unsigned)m, 0);
    c = __builtin_amdgcn_mbcnt_hi((unsigned)(m >> 32), c);
    return c;   // popcount of m over lanes strictly below this lane
}

// ---------------------------------------------------------------------------
// Kernel 1: grid-strided waves over rows; 4 nontemporal float4 loads (4 KB)
// in flight per iteration; single combined ballot skips all-zero chunks.
// Block 0 additionally zeroes the lookback state array for kernel 2 (runs
// strictly before it in stream order -> no memset dispatch needed).
// ---------------------------------------------------------------------------
__global__ void find_nb_kernel(const float* __restrict__ A,
                               int* __restrict__ nb,
                               int* __restrict__ state, int nState,
                               int N, int totalWaves) {
    if (blockIdx.x == 0) {
        for (int q = threadIdx.x; q < nState; q += blockDim.x) state[q] = 0;
    }
    const int wavesPerBlock = blockDim.x >> 6;
    const int waveId = blockIdx.x * wavesPerBlock + (threadIdx.x >> 6);
    const int lane = threadIdx.x & 63;
    const int n4 = N >> 2;

    for (int row = waveId; row < N; row += totalWaves) {
        const f4* rowp = reinterpret_cast<const f4*>(A + (long long)row * N);
        int count = 0;

        for (int c0 = 0; c0 < n4; c0 += 256) {
            const int i0 = c0 + lane;
            const int i1 = i0 + 64, i2 = i0 + 128, i3 = i0 + 192;
            f4 v0 = {0.f, 0.f, 0.f, 0.f}, v1 = {0.f, 0.f, 0.f, 0.f};
            f4 v2 = {0.f, 0.f, 0.f, 0.f}, v3 = {0.f, 0.f, 0.f, 0.f};
            if (i0 < n4) v0 = __builtin_nontemporal_load(&rowp[i0]);
            if (i1 < n4) v1 = __builtin_nontemporal_load(&rowp[i1]);
            if (i2 < n4) v2 = __builtin_nontemporal_load(&rowp[i2]);
            if (i3 < n4) v3 = __builtin_nontemporal_load(&rowp[i3]);

            const bool a0 = (v0.x != 0.f) || (v0.y != 0.f) || (v0.z != 0.f) || (v0.w != 0.f);
            const bool a1 = (v1.x != 0.f) || (v1.y != 0.f) || (v1.z != 0.f) || (v1.w != 0.f);
            const bool a2 = (v2.x != 0.f) || (v2.y != 0.f) || (v2.z != 0.f) || (v2.w != 0.f);
            const bool a3 = (v3.x != 0.f) || (v3.y != 0.f) || (v3.z != 0.f) || (v3.w != 0.f);
            if (__ballot(a0 || a1 || a2 || a3) == 0ull) continue;   // common path

            #pragma unroll
            for (int q = 0; q < 4; ++q) {
                const f4 v = (q == 0) ? v0 : (q == 1) ? v1 : (q == 2) ? v2 : v3;
                const int idx = c0 + q * 64 + lane;
                const unsigned long long m0 = __ballot(v.x != 0.f);
                const unsigned long long m1 = __ballot(v.y != 0.f);
                const unsigned long long m2 = __ballot(v.z != 0.f);
                const unsigned long long m3 = __ballot(v.w != 0.f);
                if ((m0 | m1 | m2 | m3) != 0ull) {
                    const int below = mbcnt64(m0) + mbcnt64(m1) + mbcnt64(m2) + mbcnt64(m3);
                    const int b0 = (int)((m0 >> lane) & 1ull);
                    const int b1 = (int)((m1 >> lane) & 1ull);
                    const int b2 = (int)((m2 >> lane) & 1ull);
                    const int base = count + below;
                    if (v.x != 0.f) { const int p = base;                if (p < NEI) nb[row * ROWSTRIDE + p] = (idx << 2) + 0; }
                    if (v.y != 0.f) { const int p = base + b0;           if (p < NEI) nb[row * ROWSTRIDE + p] = (idx << 2) + 1; }
                    if (v.z != 0.f) { const int p = base + b0 + b1;      if (p < NEI) nb[row * ROWSTRIDE + p] = (idx << 2) + 2; }
                    if (v.w != 0.f) { const int p = base + b0 + b1 + b2; if (p < NEI) nb[row * ROWSTRIDE + p] = (idx << 2) + 3; }
                    count += __popcll(m0) + __popcll(m1) + __popcll(m2) + __popcll(m3);
                }
            }
        }
        // tail columns if N % 4 != 0
        const int base4 = n4 << 2;
        const int rem = N - base4;
        if (rem > 0) {
            float v = 0.f;
            if (lane < rem) v = A[(long long)row * N + base4 + lane];
            const unsigned long long m = __ballot(v != 0.f);
            if (v != 0.f) {
                const int p = count + mbcnt64(m);
                if (p < NEI) nb[row * ROWSTRIDE + p] = base4 + lane;
            }
        }
    }
}

// ---------------------------------------------------------------------------
// Kernel 2 (fused tail): per-(i,j) masks + block scan + decoupled-lookback
// global prefix + emit, all in one dispatch. state[b] packs (value<<2)|flag.
// All blocks are co-resident (586 << capacity) so the lookback spin always
// makes progress; resulting positions are timing-independent.
// ---------------------------------------------------------------------------
__global__ __launch_bounds__(256) void tri_kernel(const int* __restrict__ nb,
                                                  int* __restrict__ state,
                                                  int* __restrict__ out, int N) {
    __shared__ int partial[256];
    __shared__ int s_prefix;
    const int tid = blockIdx.x * 256 + threadIdx.x;
    const int M = N * NEI;

    int c = 0, mask = 0, i = 0, j = 0, a = 0;
    int4 w0 = {0,0,0,0}, w1 = {0,0,0,0}, w2 = {0,0,0,0}, w3 = {0,0,0,0};
    if (tid < M) {
        i = tid / NEI;
        j = tid - i * NEI;
        a = nb[i * ROWSTRIDE + j];
        if (a > i) {
            const int4* np = reinterpret_cast<const int4*>(nb + a * ROWSTRIDE);
            const int4 n0 = np[0], n1 = np[1], n2 = np[2], n3 = np[3];
            const int4* vp = reinterpret_cast<const int4*>(nb + i * ROWSTRIDE);
            w0 = vp[0]; w1 = vp[1]; w2 = vp[2]; w3 = vp[3];
            #pragma unroll
            for (int k = 1; k < NEI; ++k) {
                if (k > j) {
                    const int b = GET16(w0, w1, w2, w3, k);
                    const bool adj =
                        (n0.x == b) || (n0.y == b) || (n0.z == b) || (n0.w == b) ||
                        (n1.x == b) || (n1.y == b) || (n1.z == b) || (n1.w == b) ||
                        (n2.x == b) || (n2.y == b) || (n2.z == b) || (n2.w == b) ||
                        (n3.x == b) || (n3.y == b) || (n3.z == b);
                    if (adj) { mask |= (1 << k); ++c; }
                }
            }
        }
    }

    // block-local exclusive scan (Hillis-Steele over 256)
    partial[threadIdx.x] = c;
    __syncthreads();
    #pragma unroll
    for (int d = 1; d < 256; d <<= 1) {
        const int mine  = partial[threadIdx.x];
        const int other = (threadIdx.x >= d) ? partial[threadIdx.x - d] : 0;
        __syncthreads();
        partial[threadIdx.x] = mine + other;
        __syncthreads();
    }
    const int localExcl  = (threadIdx.x == 0) ? 0 : partial[threadIdx.x - 1];
    const int blockTotal = partial[255];

    // publish own aggregate (block 0: inclusive prefix)
    if (threadIdx.x == 0) {
        const int flag = (blockIdx.x == 0) ? FLAG_PREFIX : FLAG_AGG;
        __hip_atomic_store(&state[blockIdx.x], (blockTotal << 2) | flag,
                           __ATOMIC_RELEASE, __HIP_MEMORY_SCOPE_AGENT);
        if (blockIdx.x == 0) s_prefix = 0;
    }

    // wave 0: wave-parallel decoupled lookback
    if (blockIdx.x > 0 && threadIdx.x < 64) {
        const int lane = threadIdx.x;
        int excl = 0;
        int windowHi = blockIdx.x;      // window is [windowHi-64, windowHi)
        while (true) {
            const int idx = windowHi - 64 + lane;
            int st = FLAG_PREFIX;       // idx < 0 acts as prefix of value 0
            if (idx >= 0)
                st = __hip_atomic_load(&state[idx], __ATOMIC_ACQUIRE,
                                       __HIP_MEMORY_SCOPE_AGENT);
            const int flag = st & 3;
            const unsigned long long pmask = __ballot(flag == FLAG_PREFIX);
            const unsigned long long vmask = __ballot(flag != FLAG_INVALID);
            if (pmask != 0ull) {
                const int hp = 63 - __clzll(pmask);   // nearest prefix to window top
                const unsigned long long need =
                    (hp == 0) ? ~0ull : ~((1ull << hp) - 1ull);  // lanes >= hp
                if ((vmask & need) == need) {
                    int contrib = (lane >= hp) ? (st >> 2) : 0;
                    #pragma unroll
                    for (int d = 32; d >= 1; d >>= 1) contrib += __shfl_xor(contrib, d);
                    excl += contrib;
                    if (lane == 0) {
                        s_prefix = excl;
                        __hip_atomic_store(&state[blockIdx.x],
                                           ((excl + blockTotal) << 2) | FLAG_PREFIX,
                                           __ATOMIC_RELEASE, __HIP_MEMORY_SCOPE_AGENT);
                    }
                    break;
                }
            } else if (vmask == ~0ull) {   // whole window is aggregates
                int contrib = st >> 2;
                #pragma unroll
                for (int d = 32; d >= 1; d >>= 1) contrib += __shfl_xor(contrib, d);
                excl += contrib;
                windowHi -= 64;
            }
            // else: some predecessor not yet published — spin
        }
    }
    __syncthreads();

    // emit
    if (tid < M && mask != 0) {
        int pos = s_prefix + localExcl;
        #pragma unroll
        for (int k = 1; k < NEI; ++k) {
            if ((mask >> k) & 1) {
                const int b = GET16(w0, w1, w2, w3, k);
                out[3 * pos + 0] = i;
                out[3 * pos + 1] = a;
                out[3 * pos + 2] = b;
                ++pos;
            }
        }
    }
}

extern "C" void kernel_launch(void* const* d_in, const int* in_sizes, int n_in,
                              void* d_out, int out_size, void* d_ws, size_t ws_size,
                              hipStream_t stream) {
    const float* A = (const float*)d_in[0];
    const long long total = (long long)in_sizes[0];
    const int N = (int)llround(sqrt((double)total));
    const int M = N * NEI;
    const int B2 = (M + 255) / 256;             // tail blocks / lookback states

    int* ws = (int*)d_ws;
    // Workspace (ints): nb[N*16] | state[B2]
    int* w_nb    = ws;
    int* w_state = ws + N * ROWSTRIDE;

    int* out = (int*)d_out;

    // 1) find neighbors (written already sorted ascending) + zero lookback state.
    //    Balanced grid: each wave handles an equal number of rows, all blocks
    //    resident -> no dispatch tail.
    {
        int totalWaves = (N <= 8192) ? N : (N + 1) / 2;
        const int blocks = (totalWaves + 3) / 4;
        totalWaves = blocks * 4;
        find_nb_kernel<<<blocks, 256, 0, stream>>>(A, w_nb, w_state, B2, N, totalWaves);
    }
    // 2) fused count + scan (decoupled lookback) + emit
    tri_kernel<<<B2, 256, 0, stream>>>(w_nb, w_state, out, N);
}

// Round 7
// 75.200 us; speedup vs baseline: 1.4995x; 1.4995x over previous
//
#include <hip/hip_runtime.h>
#include <math.h>

#define NEI 15
#define ROWSTRIDE 16     // pad neighbor rows to 16 ints for int4 loads

typedef float f4 __attribute__((ext_vector_type(4)));

// Compile-time component select from 4 int4s (K must be a constant after unroll)
#define GET16(n0, n1, n2, n3, K)                                   \
    ((K) < 8                                                       \
         ? ((K) < 4                                                \
                ? ((K) == 0 ? (n0).x : (K) == 1 ? (n0).y           \
                                : (K) == 2 ? (n0).z : (n0).w)      \
                : ((K) == 4 ? (n1).x : (K) == 5 ? (n1).y           \
                                : (K) == 6 ? (n1).z : (n1).w))     \
         : ((K) < 12                                               \
                ? ((K) == 8 ? (n2).x : (K) == 9 ? (n2).y           \
                                : (K) == 10 ? (n2).z : (n2).w)     \
                : ((K) == 12 ? (n3).x : (K) == 13 ? (n3).y         \
                                : (K) == 14 ? (n3).z : (n3).w)))

__device__ __forceinline__ int mbcnt64(unsigned long long m) {
    int c = __builtin_amdgcn_mbcnt_lo((unsigned)m, 0);
    c = __builtin_amdgcn_mbcnt_hi((unsigned)(m >> 32), c);
    return c;   // popcount of m over lanes strictly below this lane
}

// ---------------------------------------------------------------------------
// Kernel 1: grid-strided waves over rows; 4 nontemporal float4 loads (4 KB)
// in flight per iteration; single combined ballot skips all-zero chunks.
// Ballot + mbcnt ranking writes neighbors in ascending column order.
// ---------------------------------------------------------------------------
__global__ void find_nb_kernel(const float* __restrict__ A,
                               int* __restrict__ nb, int N, int totalWaves) {
    const int wavesPerBlock = blockDim.x >> 6;
    const int waveId = blockIdx.x * wavesPerBlock + (threadIdx.x >> 6);
    const int lane = threadIdx.x & 63;
    const int n4 = N >> 2;

    for (int row = waveId; row < N; row += totalWaves) {
        const f4* rowp = reinterpret_cast<const f4*>(A + (long long)row * N);
        int count = 0;

        for (int c0 = 0; c0 < n4; c0 += 256) {
            const int i0 = c0 + lane;
            const int i1 = i0 + 64, i2 = i0 + 128, i3 = i0 + 192;
            f4 v0 = {0.f, 0.f, 0.f, 0.f}, v1 = {0.f, 0.f, 0.f, 0.f};
            f4 v2 = {0.f, 0.f, 0.f, 0.f}, v3 = {0.f, 0.f, 0.f, 0.f};
            if (i0 < n4) v0 = __builtin_nontemporal_load(&rowp[i0]);
            if (i1 < n4) v1 = __builtin_nontemporal_load(&rowp[i1]);
            if (i2 < n4) v2 = __builtin_nontemporal_load(&rowp[i2]);
            if (i3 < n4) v3 = __builtin_nontemporal_load(&rowp[i3]);

            const bool a0 = (v0.x != 0.f) || (v0.y != 0.f) || (v0.z != 0.f) || (v0.w != 0.f);
            const bool a1 = (v1.x != 0.f) || (v1.y != 0.f) || (v1.z != 0.f) || (v1.w != 0.f);
            const bool a2 = (v2.x != 0.f) || (v2.y != 0.f) || (v2.z != 0.f) || (v2.w != 0.f);
            const bool a3 = (v3.x != 0.f) || (v3.y != 0.f) || (v3.z != 0.f) || (v3.w != 0.f);
            if (__ballot(a0 || a1 || a2 || a3) == 0ull) continue;   // common path

            #pragma unroll
            for (int q = 0; q < 4; ++q) {
                const f4 v = (q == 0) ? v0 : (q == 1) ? v1 : (q == 2) ? v2 : v3;
                const int idx = c0 + q * 64 + lane;
                const unsigned long long m0 = __ballot(v.x != 0.f);
                const unsigned long long m1 = __ballot(v.y != 0.f);
                const unsigned long long m2 = __ballot(v.z != 0.f);
                const unsigned long long m3 = __ballot(v.w != 0.f);
                if ((m0 | m1 | m2 | m3) != 0ull) {
                    const int below = mbcnt64(m0) + mbcnt64(m1) + mbcnt64(m2) + mbcnt64(m3);
                    const int b0 = (int)((m0 >> lane) & 1ull);
                    const int b1 = (int)((m1 >> lane) & 1ull);
                    const int b2 = (int)((m2 >> lane) & 1ull);
                    const int base = count + below;
                    if (v.x != 0.f) { const int p = base;                if (p < NEI) nb[row * ROWSTRIDE + p] = (idx << 2) + 0; }
                    if (v.y != 0.f) { const int p = base + b0;           if (p < NEI) nb[row * ROWSTRIDE + p] = (idx << 2) + 1; }
                    if (v.z != 0.f) { const int p = base + b0 + b1;      if (p < NEI) nb[row * ROWSTRIDE + p] = (idx << 2) + 2; }
                    if (v.w != 0.f) { const int p = base + b0 + b1 + b2; if (p < NEI) nb[row * ROWSTRIDE + p] = (idx << 2) + 3; }
                    count += __popcll(m0) + __popcll(m1) + __popcll(m2) + __popcll(m3);
                }
            }
        }
        // tail columns if N % 4 != 0
        const int base4 = n4 << 2;
        const int rem = N - base4;
        if (rem > 0) {
            float v = 0.f;
            if (lane < rem) v = A[(long long)row * N + base4 + lane];
            const unsigned long long m = __ballot(v != 0.f);
            if (v != 0.f) {
                const int p = count + mbcnt64(m);
                if (p < NEI) nb[row * ROWSTRIDE + p] = base4 + lane;
            }
        }
    }
}

// ---------------------------------------------------------------------------
// Kernel 2: per-(i,j) triangle count + 15-bit adjacency mask, fused with the
// per-block (256-wide) exclusive scan. offs2 is block-local; blockSums[b] is
// the block total. No cross-block dependencies.
// ---------------------------------------------------------------------------
__global__ void count_tri_kernel(const int* __restrict__ nb,
                                 int* __restrict__ mask2,
                                 int* __restrict__ offs2,
                                 int* __restrict__ blockSums, int N) {
    __shared__ int partial[256];
    const int tid = blockIdx.x * 256 + threadIdx.x;
    const int M = N * NEI;
    int c = 0, mask = 0;
    if (tid < M) {
        const int i = tid / NEI;
        const int j = tid - i * NEI;
        const int a = nb[i * ROWSTRIDE + j];
        if (a > i) {
            const int4* np = reinterpret_cast<const int4*>(nb + a * ROWSTRIDE);
            const int4 n0 = np[0], n1 = np[1], n2 = np[2], n3 = np[3];
            const int4* vp = reinterpret_cast<const int4*>(nb + i * ROWSTRIDE);
            const int4 w0 = vp[0], w1 = vp[1], w2 = vp[2], w3 = vp[3];
            #pragma unroll
            for (int k = 1; k < NEI; ++k) {
                if (k > j) {
                    const int b = GET16(w0, w1, w2, w3, k);
                    const bool adj =
                        (n0.x == b) || (n0.y == b) || (n0.z == b) || (n0.w == b) ||
                        (n1.x == b) || (n1.y == b) || (n1.z == b) || (n1.w == b) ||
                        (n2.x == b) || (n2.y == b) || (n2.z == b) || (n2.w == b) ||
                        (n3.x == b) || (n3.y == b) || (n3.z == b);
                    if (adj) { mask |= (1 << k); ++c; }
                }
            }
        }
        mask2[tid] = mask;
    }
    partial[threadIdx.x] = c;
    __syncthreads();
    #pragma unroll
    for (int d = 1; d < 256; d <<= 1) {
        const int mine  = partial[threadIdx.x];
        const int other = (threadIdx.x >= d) ? partial[threadIdx.x - d] : 0;
        __syncthreads();
        partial[threadIdx.x] = mine + other;
        __syncthreads();
    }
    if (tid < M) offs2[tid] = (threadIdx.x == 0) ? 0 : partial[threadIdx.x - 1];
    if (threadIdx.x == 255) blockSums[blockIdx.x] = partial[255];
}

// ---------------------------------------------------------------------------
// Kernel 3: emit. Each block first reduces blockSums[0..blockIdx) itself
// (<=586 L2-hot ints, LDS tree reduce) -- replaces the serial scan2 dispatch.
// Then decodes masks. Global order (i asc, j asc, k asc) == lexicographic.
// ---------------------------------------------------------------------------
__global__ __launch_bounds__(256) void emit_tri_kernel(const int* __restrict__ nb,
                                                       const int* __restrict__ mask2,
                                                       const int* __restrict__ offs2,
                                                       const int* __restrict__ blockSums,
                                                       int* __restrict__ out, int N) {
    __shared__ int red[256];
    const int tid = blockIdx.x * 256 + threadIdx.x;
    const int M = N * NEI;

    // block offset = sum of all previous block totals
    int s = 0;
    for (int idx = threadIdx.x; idx < blockIdx.x; idx += 256) s += blockSums[idx];
    red[threadIdx.x] = s;
    __syncthreads();
    #pragma unroll
    for (int d = 128; d >= 1; d >>= 1) {
        if (threadIdx.x < d) red[threadIdx.x] += red[threadIdx.x + d];
        __syncthreads();
    }
    const int blockOff = red[0];

    if (tid >= M) return;
    const int mask = mask2[tid];
    if (mask == 0) return;
    const int i = tid / NEI;
    const int j = tid - i * NEI;
    const int a = nb[i * ROWSTRIDE + j];
    const int4* vp = reinterpret_cast<const int4*>(nb + i * ROWSTRIDE);
    const int4 w0 = vp[0], w1 = vp[1], w2 = vp[2], w3 = vp[3];
    int pos = blockOff + offs2[tid];
    #pragma unroll
    for (int k = 1; k < NEI; ++k) {
        if ((mask >> k) & 1) {
            const int b = GET16(w0, w1, w2, w3, k);
            out[3 * pos + 0] = i;
            out[3 * pos + 1] = a;
            out[3 * pos + 2] = b;
            ++pos;
        }
    }
}

extern "C" void kernel_launch(void* const* d_in, const int* in_sizes, int n_in,
                              void* d_out, int out_size, void* d_ws, size_t ws_size,
                              hipStream_t stream) {
    const float* A = (const float*)d_in[0];
    const long long total = (long long)in_sizes[0];
    const int N = (int)llround(sqrt((double)total));
    const int M = N * NEI;
    const int B = (M + 255) / 256;              // count/emit blocks

    int* ws = (int*)d_ws;
    // Workspace (ints): nb[N*16] | mask2[M] | offs2[M] | blockSums[B]
    int* w_nb    = ws;
    int* w_mask2 = ws + N * ROWSTRIDE;
    int* w_offs2 = w_mask2 + M;
    int* w_bsum  = w_offs2 + M;

    int* out = (int*)d_out;

    // 1) find neighbors (written already sorted ascending). Balanced grid:
    //    each wave handles an equal number of rows, all blocks resident.
    {
        int totalWaves = (N <= 8192) ? N : (N + 1) / 2;
        const int blocks = (totalWaves + 3) / 4;
        totalWaves = blocks * 4;
        find_nb_kernel<<<blocks, 256, 0, stream>>>(A, w_nb, N, totalWaves);
    }
    // 2) count per (i,j) + adjacency masks + fused per-block scan
    count_tri_kernel<<<B, 256, 0, stream>>>(w_nb, w_mask2, w_offs2, w_bsum, N);
    // 3) emit (per-block offset reduced in-kernel; no serial scan dispatch)
    emit_tri_kernel<<<B, 256, 0, stream>>>(w_nb, w_mask2, w_offs2, w_bsum, out, N);
}